// Round 17
// baseline (342.328 us; speedup 1.0000x reference)
//
#include <hip/hip_runtime.h>
#include <cstdint>
#include <cstddef>

using short8   = __attribute__((ext_vector_type(8))) short;
using f32x4    = __attribute__((ext_vector_type(4))) float;
using ushort4v = __attribute__((ext_vector_type(4))) unsigned short;

#define DEV static __device__ __forceinline__

constexpr int NB  = 4;
constexpr int SEQ = 4096;
constexpr int DM  = 1024;
constexpr int BSR = NB * SEQ;            // 16384 flattened rows
constexpr size_t PBSTR = 136ULL * 65536; // per-batch panel elems (fp16/bf16)

DEV unsigned short f2bf(float f) {
  union { float f; unsigned u; } v; v.f = f;
  unsigned r = v.u + 0x7FFFu + ((v.u >> 16) & 1u);  // RNE
  return (unsigned short)(r >> 16);
}

DEV int tri(int t) { return t * (t + 1) / 2; }

DEV void gload_lds16(const void* g, void* l) {
  __builtin_amdgcn_global_load_lds(
      (__attribute__((address_space(1))) void*)(g),
      (__attribute__((address_space(3))) void*)(l), 16, 0, 0);
}

DEV f32x4 mfma16(short8 a, short8 b, f32x4 c) {
  return __builtin_amdgcn_mfma_f32_16x16x32_bf16(a, b, c, 0, 0, 0);
}

DEV void bar() { asm volatile("s_barrier" ::: "memory"); }

// RoPE-pair permutation: orig row index for permuted position p.
DEV int orig_row(int p) {
  int gI = p >> 5, rr = p & 31;
  return (rr < 16) ? (gI * 16 + rr) : (512 + gI * 16 + (rr - 16));
}

// ---------------- conversion / permutation ----------------
__global__ __launch_bounds__(256) void convert_kernel(
    const float* __restrict__ x,
    const float* __restrict__ Wq, const float* __restrict__ Wk, const float* __restrict__ Wv,
    const float* __restrict__ bq, const float* __restrict__ bk, const float* __restrict__ bv,
    unsigned short* __restrict__ xbf,
    unsigned short* __restrict__ Wqp, unsigned short* __restrict__ Wkp, unsigned short* __restrict__ Wvp,
    float* __restrict__ bqp, float* __restrict__ bkp, float* __restrict__ bvp)
{
  const int U1 = BSR * DM / 8;
  const int U2 = 2 * DM * DM / 8;
  const int U3 = DM * DM / 8;
  const int U4 = 3 * DM / 8;
  const int total = U1 + U2 + U3 + U4;
  for (int u = blockIdx.x * blockDim.x + threadIdx.x; u < total;
       u += gridDim.x * blockDim.x) {
    if (u < U1) {
      int e = u * 8;
      float4 f0 = ((const float4*)(x + e))[0];
      float4 f1 = ((const float4*)(x + e))[1];
      short8 o;
      o[0]=(short)f2bf(f0.x); o[1]=(short)f2bf(f0.y); o[2]=(short)f2bf(f0.z); o[3]=(short)f2bf(f0.w);
      o[4]=(short)f2bf(f1.x); o[5]=(short)f2bf(f1.y); o[6]=(short)f2bf(f1.z); o[7]=(short)f2bf(f1.w);
      *(short8*)(xbf + e) = o;
    } else if (u < U1 + U2) {
      int w = u - U1;
      int which = w >> 17;
      int r = w & (131072 - 1);
      int p = r >> 7;
      int m8 = (r & 127) * 8;
      const float* src = (which ? Wk : Wq) + (size_t)orig_row(p) * DM + m8;
      unsigned short* dst = (which ? Wkp : Wqp) + (size_t)p * DM + m8;
      float4 f0 = ((const float4*)src)[0];
      float4 f1 = ((const float4*)src)[1];
      short8 o;
      o[0]=(short)f2bf(f0.x); o[1]=(short)f2bf(f0.y); o[2]=(short)f2bf(f0.z); o[3]=(short)f2bf(f0.w);
      o[4]=(short)f2bf(f1.x); o[5]=(short)f2bf(f1.y); o[6]=(short)f2bf(f1.z); o[7]=(short)f2bf(f1.w);
      *(short8*)dst = o;
    } else if (u < U1 + U2 + U3) {
      int r = u - (U1 + U2);
      int p = r >> 7;
      int m8 = (r & 127) * 8;
      const float* src = Wv + (size_t)p * DM + m8;
      float4 f0 = ((const float4*)src)[0];
      float4 f1 = ((const float4*)src)[1];
      short8 o;
      o[0]=(short)f2bf(f0.x); o[1]=(short)f2bf(f0.y); o[2]=(short)f2bf(f0.z); o[3]=(short)f2bf(f0.w);
      o[4]=(short)f2bf(f1.x); o[5]=(short)f2bf(f1.y); o[6]=(short)f2bf(f1.z); o[7]=(short)f2bf(f1.w);
      *(short8*)(Wvp + (size_t)p * DM + m8) = o;
    } else {
      int t = u - (U1 + U2 + U3);
      int which = t >> 7;
      int i0 = (t & 127) * 8;
      for (int e = 0; e < 8; ++e) {
        int p = i0 + e;
        if (which == 0)      bqp[p] = bq[orig_row(p)];
        else if (which == 1) bkp[p] = bk[orig_row(p)];
        else                 bvp[p] = bv[p];
      }
    }
  }
}

// ================= 8-phase 256x256x1024 GEMM core =================
// BK=64, 16 K-steps, 8 iterations. LDS (elems): dbuf d at d*32768:
//   A.k0 @0, A.k1 @8192, B.k0 @16384, B.k1 @24576  (each 256 rows x 32 cols)
// vmcnt(6) at even-phase tops (counted, never 0 in-loop).
// Swizzle: colgroup ^= (row>>1)&3 both sides.

template <int DB, int MH, int KS, bool RB, int SREG, bool DOVM>
DEV void phase8(unsigned short* lds, const unsigned short* SG, int scol,
                const int (&aoff)[2][4], const int (&boff)[4], int tid,
                short8 (&bv)[4], f32x4 (&acc)[8][4])
{
  if (DOVM) asm volatile("s_waitcnt vmcnt(6)" ::: "memory");
  gload_lds16(SG + (size_t)(tid >> 2) * 1024 + scol,
              (void*)(lds + SREG + tid * 8));
  gload_lds16(SG + (size_t)((tid >> 2) + 128) * 1024 + scol,
              (void*)(lds + SREG + 4096 + tid * 8));
  short8 av[4];
  #pragma unroll
  for (int f = 0; f < 4; ++f)
    av[f] = *(const short8*)(lds + DB + KS * 8192 + aoff[MH][f]);
  if (RB) {
    #pragma unroll
    for (int f = 0; f < 4; ++f)
      bv[f] = *(const short8*)(lds + DB + 16384 + KS * 8192 + boff[f]);
  }
  bar();
  __builtin_amdgcn_s_setprio(1);
  #pragma unroll
  for (int fm = 0; fm < 4; ++fm)
    #pragma unroll
    for (int fn = 0; fn < 4; ++fn)
      acc[MH * 4 + fm][fn] = mfma16(av[fm], bv[fn], acc[MH * 4 + fm][fn]);
  __builtin_amdgcn_s_setprio(0);
  bar();
}

DEV void run_gemm8(unsigned short* lds,
                   const unsigned short* __restrict__ Ag,
                   const unsigned short* __restrict__ Bg,
                   int tid, int lane, int wm, int wn,
                   f32x4 (&acc)[8][4])
{
  const int c = lane & 15, g = lane >> 4;
  const int gsw = (g ^ ((c >> 1) & 3)) * 8;
  const int scg = (((tid & 3) ^ ((tid >> 3) & 3))) * 8;   // pre-swizzled stage col
  int aoff[2][4], boff[4];
  #pragma unroll
  for (int mh = 0; mh < 2; ++mh)
    #pragma unroll
    for (int f = 0; f < 4; ++f)
      aoff[mh][f] = (wm * 128 + mh * 64 + f * 16 + c) * 32 + gsw;
  #pragma unroll
  for (int f = 0; f < 4; ++f)
    boff[f] = (wn * 64 + f * 16 + c) * 32 + gsw;

  // prologue: d0 <- step0 (4 halves), d1.k0 <- step1 (2 halves)
  {
    const int r0 = tid >> 2;
    gload_lds16(Ag + (size_t)r0 * 1024 + scg,              (void*)(lds + tid * 8));
    gload_lds16(Ag + (size_t)(r0 + 128) * 1024 + scg,      (void*)(lds + 4096 + tid * 8));
    gload_lds16(Bg + (size_t)r0 * 1024 + scg,              (void*)(lds + 16384 + tid * 8));
    gload_lds16(Bg + (size_t)(r0 + 128) * 1024 + scg,      (void*)(lds + 16384 + 4096 + tid * 8));
    gload_lds16(Ag + (size_t)r0 * 1024 + 32 + scg,         (void*)(lds + 8192 + tid * 8));
    gload_lds16(Ag + (size_t)(r0 + 128) * 1024 + 32 + scg, (void*)(lds + 8192 + 4096 + tid * 8));
    gload_lds16(Bg + (size_t)r0 * 1024 + 32 + scg,         (void*)(lds + 24576 + tid * 8));
    gload_lds16(Bg + (size_t)(r0 + 128) * 1024 + 32 + scg, (void*)(lds + 24576 + 4096 + tid * 8));
    gload_lds16(Ag + (size_t)r0 * 1024 + 64 + scg,         (void*)(lds + 32768 + tid * 8));
    gload_lds16(Ag + (size_t)(r0 + 128) * 1024 + 64 + scg, (void*)(lds + 32768 + 4096 + tid * 8));
    gload_lds16(Bg + (size_t)r0 * 1024 + 64 + scg,         (void*)(lds + 49152 + tid * 8));
    gload_lds16(Bg + (size_t)(r0 + 128) * 1024 + 64 + scg, (void*)(lds + 49152 + 4096 + tid * 8));
  }
  asm volatile("s_waitcnt vmcnt(4)" ::: "memory");
  bar();

  short8 bv[4];
  for (int it = 0; it < 8; ++it) {
    const int s1 = 2 * it + 1;
    const int s2 = (2 * it + 2 < 16) ? 2 * it + 2 : 15;
    const int s3 = (2 * it + 3 < 16) ? 2 * it + 3 : 15;
    const int c1  = s1 * 64 + 32 + scg;   // s1.k1
    const int c2a = s2 * 64 + scg;        // s2.k0
    const int c2b = s2 * 64 + 32 + scg;   // s2.k1
    const int c3  = s3 * 64 + scg;        // s3.k0
    phase8<0,     0, 0, true,  40960, false>(lds, Ag, c1,  aoff, boff, tid, bv, acc);
    phase8<0,     1, 0, false, 57344, true >(lds, Bg, c1,  aoff, boff, tid, bv, acc);
    phase8<0,     0, 1, true,  0,     false>(lds, Ag, c2a, aoff, boff, tid, bv, acc);
    phase8<0,     1, 1, false, 16384, true >(lds, Bg, c2a, aoff, boff, tid, bv, acc);
    phase8<32768, 0, 0, true,  8192,  false>(lds, Ag, c2b, aoff, boff, tid, bv, acc);
    phase8<32768, 1, 0, false, 24576, true >(lds, Bg, c2b, aoff, boff, tid, bv, acc);
    phase8<32768, 0, 1, true,  32768, false>(lds, Ag, c3,  aoff, boff, tid, bv, acc);
    phase8<32768, 1, 1, false, 49152, true >(lds, Bg, c3,  aoff, boff, tid, bv, acc);
  }
  asm volatile("s_waitcnt vmcnt(0)" ::: "memory");
}

// ---------------- generic 256x128xK double-buffered core (r5-proven) ----------------
template <int CN>
DEV void stage_pv(const unsigned short* g, size_t ld, size_t k0,
                  unsigned short* ldst, int sdst, int srow, int scg8) {
  #pragma unroll
  for (int cc = 0; cc < CN; ++cc)
    gload_lds16(g + (size_t)(cc * 128 + srow) * ld + k0 + scg8,
                (void*)(ldst + cc * 4096 + sdst));
}

DEV void run_gemm_pv(unsigned short* lds,
                     const unsigned short* __restrict__ Ag, size_t lda,
                     const unsigned short* __restrict__ Bg, size_t ldb,
                     int NT, int tid, int lane, int wm, int wn,
                     f32x4 (&acc)[4][4])
{
  constexpr int BUFE = (256 + 128) * 32;
  const int srow = tid >> 2;
  const int scg8 = (((tid & 3) ^ ((srow >> 1) & 3))) * 8;
  const int sdst = srow * 32 + (tid & 3) * 8;
  const int c = lane & 15, g = lane >> 4;
  const int gsw = (g ^ ((c >> 1) & 3)) * 8;
  int aoff[4], boff[4];
  #pragma unroll
  for (int f = 0; f < 4; ++f) aoff[f] = (wm * 64 + f * 16 + c) * 32 + gsw;
  #pragma unroll
  for (int f = 0; f < 4; ++f) boff[f] = 256 * 32 + (wn * 64 + f * 16 + c) * 32 + gsw;

  #pragma unroll
  for (int p = 0; p < 3; ++p) {
    stage_pv<2>(Ag, lda, (size_t)p * 32, lds + p * BUFE, sdst, srow, scg8);
    stage_pv<1>(Bg, ldb, (size_t)p * 32, lds + p * BUFE + 256 * 32, sdst, srow, scg8);
  }

  for (int t = 0; t < NT; ++t) {
    const int bsel = t & 3, nsel = (t + 3) & 3;
    const size_t ts = (size_t)((t + 3 < NT) ? t + 3 : NT - 1);
    unsigned short* lb = lds + bsel * BUFE;
    stage_pv<2>(Ag, lda, ts * 32, lds + nsel * BUFE, sdst, srow, scg8);
    asm volatile("s_waitcnt vmcnt(7)" ::: "memory");
    bar();
    short8 av[2], bv[4];
    #pragma unroll
    for (int f = 0; f < 2; ++f) av[f] = *(const short8*)(lb + aoff[f]);
    #pragma unroll
    for (int f = 0; f < 4; ++f) bv[f] = *(const short8*)(lb + boff[f]);
    __builtin_amdgcn_s_setprio(1);
    #pragma unroll
    for (int mf = 0; mf < 2; ++mf)
      #pragma unroll
      for (int nf = 0; nf < 4; ++nf)
        acc[mf][nf] = mfma16(av[mf], bv[nf], acc[mf][nf]);
    __builtin_amdgcn_s_setprio(0);
    stage_pv<1>(Bg, ldb, ts * 32, lds + nsel * BUFE + 256 * 32, sdst, srow, scg8);
    #pragma unroll
    for (int f = 0; f < 2; ++f) av[f] = *(const short8*)(lb + aoff[2 + f]);
    __builtin_amdgcn_s_setprio(1);
    #pragma unroll
    for (int mf = 0; mf < 2; ++mf)
      #pragma unroll
      for (int nf = 0; nf < 4; ++nf)
        acc[2 + mf][nf] = mfma16(av[mf], bv[nf], acc[2 + mf][nf]);
    __builtin_amdgcn_s_setprio(0);
    bar();
  }
  asm volatile("s_waitcnt vmcnt(0)" ::: "memory");
}

// ---------------- projection GEMM (lean template: MODE 0 rope, MODE 1 V^T) ----------------
// Separate instantiation from scores/pv paths (rule #19: co-compiled template
// variants perturb codegen; the lean proj runs ~38us/round, merged ran 52).
template <int MODE>
__global__ __launch_bounds__(512, 2) void k_proj(
    const unsigned short* __restrict__ X,
    const unsigned short* __restrict__ W,
    const float* __restrict__ bias,
    const float* __restrict__ cosT, const float* __restrict__ sinT,
    unsigned short* __restrict__ out)
{
  __shared__ unsigned short lds[65536];  // 128 KiB
  const int tid = threadIdx.x, lane = tid & 63, wid = tid >> 6;
  const int wm = wid >> 2, wn = wid & 3;     // 2 x 4 waves
  const int c = lane & 15, g = lane >> 4;

  const int xcd = blockIdx.x & 7, idx = blockIdx.x >> 3;
  const int bm = (xcd * 8 + (idx >> 2)) * 256;
  const int bn = (idx & 3) * 256;
  const unsigned short* Ag = X + (size_t)bm * DM;
  const unsigned short* Bg = W + (size_t)bn * DM;

  f32x4 z4 = {0.f, 0.f, 0.f, 0.f};
  f32x4 acc[8][4];
  #pragma unroll
  for (int m = 0; m < 8; ++m)
    #pragma unroll
    for (int n = 0; n < 4; ++n) acc[m][n] = z4;

  run_gemm8(lds, Ag, Bg, tid, lane, wm, wn, acc);

  if (MODE == 0) {
    #pragma unroll
    for (int am = 0; am < 8; ++am) {
      int row0 = bm + wm * 128 + (am >> 2) * 64 + (am & 3) * 16 + g * 4;
      #pragma unroll
      for (int fp = 0; fp < 4; fp += 2) {
        int f_g = (bn >> 4) + wn * 4 + fp;
        float b0f = bias[f_g * 16 + c];
        float b1f = bias[f_g * 16 + 16 + c];
        int j = (f_g >> 1) * 16 + c;
        #pragma unroll
        for (int r = 0; r < 4; ++r) {
          int rowg = row0 + r;
          int s = rowg & (SEQ - 1);
          float x0 = acc[am][fp][r] + b0f;
          float x1 = acc[am][fp + 1][r] + b1f;
          float cv = cosT[(size_t)s * (DM / 2) + j];
          float sv = sinT[(size_t)s * (DM / 2) + j];
          out[(size_t)rowg * DM + f_g * 16 + c]      = f2bf(x0 * cv - x1 * sv);
          out[(size_t)rowg * DM + f_g * 16 + 16 + c] = f2bf(x0 * sv + x1 * cv);
        }
      }
    }
  } else {
    #pragma unroll
    for (int am = 0; am < 8; ++am) {
      int s0 = bm + wm * 128 + (am >> 2) * 64 + (am & 3) * 16 + g * 4;
      int bb = s0 >> 12;
      int sl = s0 & (SEQ - 1);
      #pragma unroll
      for (int fn = 0; fn < 4; ++fn) {
        int v = bn + wn * 64 + fn * 16 + c;
        float bv_ = bias[v];
        ushort4v pk;
        #pragma unroll
        for (int r = 0; r < 4; ++r) pk[r] = f2bf(acc[am][fn][r] + bv_);
        *(ushort4v*)(out + ((size_t)(bb * DM + v)) * SEQ + sl) = pk;
      }
    }
  }
}

// ---------------- scores kernel (8-phase core, half-split packing) ----------------
// Scores -> per-256-row causal panels, raw fp16.
//   G==4 half-split schedule (256 blocks; per XCD 32 blocks / 68 tiles):
//     idx<24:  {2 fulls}                      = 2.0T
//     idx>=24: {2 fulls + one 256x128 half}   = 2.54T  (4 tiles -> 8 halves)
//   Half-granularity makespan floor is 2.5T (loads in 0.5-multiples, 68/32);
//   uniform-integral packing was 3T. Measured 104.5us vs 111.5 (r12).
__global__ __launch_bounds__(512, 2) void k_scores(
    const unsigned short* __restrict__ Ain,
    const unsigned short* __restrict__ Bin,
    unsigned short* __restrict__ out, int b0, int G)
{
  __shared__ unsigned short lds[65536];  // 128 KiB
  const int tid = threadIdx.x, lane = tid & 63, wid = tid >> 6;
  const int wm = wid >> 2, wn = wid & 3;     // 2 x 4 waves (full core)
  const int c = lane & 15, g = lane >> 4;

  const int xcd = blockIdx.x & 7, idx = blockIdx.x >> 3;
  int t0, t1, ths = -1, hh = 0;
  if (G == 4) {
    const int base = xcd * 68;
    if (idx < 24) { t0 = base + 2 * idx; t1 = t0 + 1; }
    else {
      int k = idx - 24;
      t0 = base + 48 + 2 * k; t1 = t0 + 1;
      ths = base + 64 + (k >> 1); hh = k & 1;
    }
  } else {
    const int lin0 = xcd * (17 * G) + idx;
    t0 = lin0;
    t1 = (idx < G) ? (xcd * (17 * G) + 16 * G + idx) : -1;
  }

  for (int j = 0; j < 2; ++j) {
    const int t = j ? t1 : t0;
    if (t < 0) break;
    const int li = t / 136;
    const int t136 = t - li * 136;
    int tm = (int)((sqrtf(8.0f * (float)t136 + 1.0f) - 1.0f) * 0.5f);
    while (tri(tm + 1) <= t136) ++tm;
    while (tri(tm) > t136) --tm;
    const int tn = t136 - tri(tm);
    const int b = b0 + li;
    const unsigned short* Ag = Ain + ((size_t)b * SEQ + tm * 256) * DM;
    const unsigned short* Bg = Bin + ((size_t)b * SEQ + tn * 256) * DM;

    f32x4 z4 = {0.f, 0.f, 0.f, 0.f};
    f32x4 acc[8][4];
    #pragma unroll
    for (int m = 0; m < 8; ++m)
      #pragma unroll
      for (int n = 0; n < 4; ++n) acc[m][n] = z4;

    run_gemm8(lds, Ag, Bg, tid, lane, wm, wn, acc);

    const size_t Kp = (size_t)(tm + 1) * 256;
    unsigned short* pb = out + (size_t)li * PBSTR + (size_t)tri(tm) * 65536;
    #pragma unroll
    for (int am = 0; am < 8; ++am) {
      int lrow = wm * 128 + (am >> 2) * 64 + (am & 3) * 16 + g * 4;
      #pragma unroll
      for (int fn = 0; fn < 4; ++fn) {
        int col = tn * 256 + wn * 64 + fn * 16 + c;
        #pragma unroll
        for (int r = 0; r < 4; ++r) {
          union { _Float16 h; unsigned short u; } cv;
          cv.h = (_Float16)acc[am][fn][r];
          pb[(size_t)(lrow + r) * Kp + col] = cv.u;
        }
      }
    }
    __syncthreads();  // LDS fully consumed before next job's staging
  }

  if (ths >= 0) {
    // 256x128 half-tile via the pv core (wave layout 4x2)
    const int wmp = wid >> 1, wnp = wid & 1;
    const int li = ths / 136;
    const int t136 = ths - li * 136;
    int tm = (int)((sqrtf(8.0f * (float)t136 + 1.0f) - 1.0f) * 0.5f);
    while (tri(tm + 1) <= t136) ++tm;
    while (tri(tm) > t136) --tm;
    const int tn = t136 - tri(tm);
    const int b = b0 + li;
    const unsigned short* Ag = Ain + ((size_t)b * SEQ + tm * 256) * DM;
    const unsigned short* Bg = Bin + ((size_t)b * SEQ + tn * 256 + hh * 128) * DM;

    f32x4 z4 = {0.f, 0.f, 0.f, 0.f};
    f32x4 acch[4][4];
    #pragma unroll
    for (int m = 0; m < 4; ++m)
      #pragma unroll
      for (int n = 0; n < 4; ++n) acch[m][n] = z4;

    run_gemm_pv(lds, Ag, DM, Bg, DM, 32, tid, lane, wmp, wnp, acch);

    const size_t Kp = (size_t)(tm + 1) * 256;
    unsigned short* pb = out + (size_t)li * PBSTR + (size_t)tri(tm) * 65536;
    #pragma unroll
    for (int am = 0; am < 4; ++am) {
      int lrow = wmp * 64 + am * 16 + g * 4;
      #pragma unroll
      for (int fn = 0; fn < 4; ++fn) {
        int col = tn * 256 + hh * 128 + wnp * 64 + fn * 16 + c;
        #pragma unroll
        for (int r = 0; r < 4; ++r) {
          union { _Float16 h; unsigned short u; } cv;
          cv.h = (_Float16)acch[am][fn][r];
          pb[(size_t)(lrow + r) * Kp + col] = cv.u;
        }
      }
    }
  }
}

// ---------------- row softmax over panels (in place, uint2-vectorized) ----------------
__global__ __launch_bounds__(256) void softmax_panel(unsigned short* __restrict__ S_)
{
  const int tid = threadIdx.x, wid = tid >> 6, lane = tid & 63;
  const int widx = blockIdx.x * 4 + wid;
  const int li = widx >> 12;
  const int r = widx & (SEQ - 1);
  const int p = r >> 8;
  const size_t Kp = (size_t)(p + 1) * 256;
  const int nt = p + 1;                     // 256-col chunks
  unsigned short* base = S_ + (size_t)li * PBSTR + (size_t)tri(p) * 65536 +
                         (size_t)(r & 255) * Kp;
  const float K2 = 0.04508422002778011f;    // (1/32) * log2(e)

  float v[16][4];
  float mx = -3.0e38f;
  #pragma unroll
  for (int ch = 0; ch < 16; ++ch) {
    if (ch < nt) {
      uint2 u = *(const uint2*)(base + ch * 256 + lane * 4);
      union { unsigned u; _Float16 h[2]; } c0, c1;
      c0.u = u.x; c1.u = u.y;
      int col = ch * 256 + lane * 4;
      float a0 = (col     <= r) ? (float)c0.h[0] : -3.0e38f;
      float a1 = (col + 1 <= r) ? (float)c0.h[1] : -3.0e38f;
      float a2 = (col + 2 <= r) ? (float)c1.h[0] : -3.0e38f;
      float a3 = (col + 3 <= r) ? (float)c1.h[1] : -3.0e38f;
      v[ch][0] = a0; v[ch][1] = a1; v[ch][2] = a2; v[ch][3] = a3;
      mx = fmaxf(fmaxf(mx, fmaxf(a0, a1)), fmaxf(a2, a3));
    }
  }
  #pragma unroll
  for (int d = 1; d < 64; d <<= 1) mx = fmaxf(mx, __shfl_xor(mx, d, 64));
  float sum = 0.f;
  #pragma unroll
  for (int ch = 0; ch < 16; ++ch) {
    if (ch < nt) {
      #pragma unroll
      for (int e = 0; e < 4; ++e) {
        float pe = (v[ch][e] < -1.0e37f) ? 0.f : exp2f((v[ch][e] - mx) * K2);
        v[ch][e] = pe;
        sum += pe;
      }
    }
  }
  #pragma unroll
  for (int d = 1; d < 64; d <<= 1) sum += __shfl_xor(sum, d, 64);
  float inv = 1.0f / sum;
  #pragma unroll
  for (int ch = 0; ch < 16; ++ch) {
    if (ch < nt) {
      uint2 o;
      o.x = (unsigned)f2bf(v[ch][0] * inv) | ((unsigned)f2bf(v[ch][1] * inv) << 16);
      o.y = (unsigned)f2bf(v[ch][2] * inv) | ((unsigned)f2bf(v[ch][3] * inv) << 16);
      *(uint2*)(base + ch * 256 + lane * 4) = o;
    }
  }
}

// ---------------- PV GEMM ----------------
// BM=256 (one panel), BN=128; 8 waves 4x2; paired panels (p, 15-p) per block.
// XCD-chunked: XCD x owns jobs jid = x*G + (j>>3).
__global__ __launch_bounds__(512, 2) void k_pv(
    const unsigned short* __restrict__ P,
    const unsigned short* __restrict__ Vt,
    float* __restrict__ z, int b0, int G)
{
  __shared__ unsigned short lds[4 * 12288];  // 96 KiB
  const int tid = threadIdx.x, lane = tid & 63, wid = tid >> 6;
  const int wm = wid >> 1, wn = wid & 1;     // 4 x 2 waves
  const int c = lane & 15, g = lane >> 4;
  const int x = blockIdx.x & 7;
  const int j = blockIdx.x >> 3;
  const int jid = x * G + (j >> 3);
  const int n8 = j & 7;
  const int li = jid >> 3;
  const int pl = jid & 7;
  const int b = b0 + li;
  const unsigned short* Bg = Vt + ((size_t)b * DM + n8 * 128) * SEQ;

  for (int h = 0; h < 2; ++h) {
    const int p = h ? (15 - pl) : pl;
    const int NT = (p + 1) * 8;
    const size_t Kp = (size_t)(p + 1) * 256;
    const unsigned short* panel = P + (size_t)li * PBSTR + (size_t)tri(p) * 65536;

    f32x4 z4 = {0.f, 0.f, 0.f, 0.f};
    f32x4 acc[4][4];
    #pragma unroll
    for (int m = 0; m < 4; ++m)
      #pragma unroll
      for (int n = 0; n < 4; ++n) acc[m][n] = z4;

    run_gemm_pv(lds, panel, Kp, Bg, SEQ, NT, tid, lane, wm, wn, acc);

    #pragma unroll
    for (int am = 0; am < 4; ++am) {
      int row = p * 256 + wm * 64 + am * 16 + g * 4;
      #pragma unroll
      for (int fn = 0; fn < 4; ++fn) {
        int col = n8 * 128 + wn * 64 + fn * 16 + c;
        #pragma unroll
        for (int r = 0; r < 4; ++r)
          z[((size_t)(b * SEQ + row + r)) * DM + col] = acc[am][fn][r];
      }
    }
    __syncthreads();
  }
}

extern "C" void kernel_launch(void* const* d_in, const int* in_sizes, int n_in,
                              void* d_out, int out_size, void* d_ws, size_t ws_size,
                              hipStream_t stream) {
  const float* x    = (const float*)d_in[0];
  const float* cosT = (const float*)d_in[1];
  const float* sinT = (const float*)d_in[2];
  const float* Wq   = (const float*)d_in[3];
  const float* bq   = (const float*)d_in[4];
  const float* Wk   = (const float*)d_in[5];
  const float* bk   = (const float*)d_in[6];
  const float* Wv   = (const float*)d_in[7];
  const float* bv   = (const float*)d_in[8];
  float* z = (float*)d_out;

  char* ws = (char*)d_ws;
  unsigned short* xbf = (unsigned short*)(ws);
  unsigned short* Wqp = (unsigned short*)(ws + 33554432);
  unsigned short* Wkp = (unsigned short*)(ws + 35651584);
  unsigned short* Wvp = (unsigned short*)(ws + 37748736);
  float* bqp = (float*)(ws + 39845888);
  float* bkp = (float*)(ws + 39849984);
  float* bvp = (float*)(ws + 39854080);
  unsigned short* Qbf = (unsigned short*)(ws + 39858176);
  unsigned short* Kbf = (unsigned short*)(ws + 73412608);
  unsigned short* Vtb = (unsigned short*)(ws + 106967040);
  const size_t BASE = 140521472ULL;
  const size_t PER  = PBSTR * 2ULL;
  unsigned short* Sc = (unsigned short*)(ws + BASE);

  int G = 1;
  if (ws_size >= BASE + 4 * PER)      G = 4;
  else if (ws_size >= BASE + 2 * PER) G = 2;

  convert_kernel<<<dim3(2048), dim3(256), 0, stream>>>(
      x, Wq, Wk, Wv, bq, bk, bv, xbf, Wqp, Wkp, Wvp, bqp, bkp, bvp);

  k_proj<0><<<dim3(256), dim3(512), 0, stream>>>(xbf, Wqp, bqp, cosT, sinT, Qbf);
  k_proj<0><<<dim3(256), dim3(512), 0, stream>>>(xbf, Wkp, bkp, cosT, sinT, Kbf);
  k_proj<1><<<dim3(256), dim3(512), 0, stream>>>(xbf, Wvp, bvp, cosT, sinT, Vtb);

  for (int b0 = 0; b0 < NB; b0 += G) {
    const int nblk = (G == 4) ? 256 : 128 * G;
    k_scores<<<dim3(nblk), dim3(512), 0, stream>>>(Qbf, Kbf, Sc, b0, G);
    softmax_panel<<<dim3(1024 * G), dim3(256), 0, stream>>>(Sc);
    k_pv<<<dim3(64 * G), dim3(512), 0, stream>>>(Sc, Vtb, z, b0, G);
  }
}